// Round 1
// baseline (170.498 us; speedup 1.0000x reference)
//
#include <hip/hip_runtime.h>
#include <hip/hip_cooperative_groups.h>

namespace cg = cooperative_groups;

// N=32, CIN=64, COUT=128, K=4, H=W=64
#define Nn     32
#define CIN    64
#define COUT   128
#define HWVOL  4096                 // H*W
#define PLANES (Nn * CIN)           // 2048
#define WBLKS  ((CIN * COUT) / 256) // 32 blocks worth of weight sums
#define GRID   1024                 // 2 planes per block; exactly 4 blocks/CU
#define OHW_INV (1.0f / 4489.0f)    // 1/67^2
#define NEGBIG (-3.0e38f)

// ---------------------------------------------------------------------------
// Fused cooperative kernel: one dispatch total.
//   Phase A: each block sums 2 x-planes (coalesced float4); blocks 0..31 also
//            compute the 8192 weight-tap sums Sw[o].
//   grid.sync()
//   Phase B: blocks 0..31: block n computes pooled[n,:] = Sx[n,:]·Sw/4489
//            + biases, then 10*logsumexp -> out[n].
// LDS ~350 B, __launch_bounds__(256,4) caps VGPR at 128 => 4 blocks/CU
// guaranteed co-resident (1024 blocks on 256 CUs).
// ---------------------------------------------------------------------------
__global__ __launch_bounds__(256, 4) void fused_kernel(
    const float* __restrict__ x,
    const float* __restrict__ w,
    const float* __restrict__ conv_bias,
    const float* __restrict__ extra_bias,
    float* __restrict__ Sx,
    float* __restrict__ Sw,
    float* __restrict__ out)
{
    const int b = blockIdx.x;
    const int t = threadIdx.x;

    // ---------------- Phase A: plane sums (+ weight sums on blocks 0..31)
    {
        const float4* p0 = (const float4*)(x + (size_t)b * HWVOL);
        const float4* p1 = (const float4*)(x + (size_t)(b + GRID) * HWVOL);
        float a0 = 0.0f, a1 = 0.0f;
#pragma unroll
        for (int j = 0; j < 4; ++j) {
            float4 u = p0[t + 256 * j];
            float4 v = p1[t + 256 * j];
            a0 += (u.x + u.y) + (u.z + u.w);
            a1 += (v.x + v.y) + (v.z + v.w);
        }
#pragma unroll
        for (int off = 32; off > 0; off >>= 1) {
            a0 += __shfl_down(a0, off, 64);
            a1 += __shfl_down(a1, off, 64);
        }
        __shared__ float part0[4], part1[4];
        if ((t & 63) == 0) { part0[t >> 6] = a0; part1[t >> 6] = a1; }
        __syncthreads();
        if (t == 0)  Sx[b]        = (part0[0] + part0[1]) + (part0[2] + part0[3]);
        if (t == 64) Sx[b + GRID] = (part1[0] + part1[1]) + (part1[2] + part1[3]);

        if (b < WBLKS) {
            const int o = b * 256 + t;               // 0..8191
            const float4* wp = (const float4*)(w + (size_t)o * 16);
            float4 a = wp[0], c = wp[1], d = wp[2], e = wp[3];
            Sw[o] = (((a.x + a.y) + (a.z + a.w)) + ((c.x + c.y) + (c.z + c.w))) +
                    (((d.x + d.y) + (d.z + d.w)) + ((e.x + e.y) + (e.z + e.w)));
        }
    }

    cg::this_grid().sync();

    // ---------------- Phase B: 32 blocks, block n -> out[n]
    if (b >= Nn) return;
    const int n = b;

    __shared__ float sxs[CIN];
    if (t < CIN) sxs[t] = Sx[n * CIN + t];
    __syncthreads();

    float pooled = NEGBIG;
    if (t < COUT) {
        float acc = 0.0f;
#pragma unroll 8
        for (int ci = 0; ci < CIN; ++ci)
            acc = fmaf(sxs[ci], Sw[ci * COUT + t], acc);
        pooled = acc * OHW_INV + conv_bias[t] + extra_bias[t];
    }

    // logsumexp across 128 live lanes (4 waves in block; waves 2,3 hold NEGBIG)
    float m = pooled;
#pragma unroll
    for (int off = 32; off > 0; off >>= 1)
        m = fmaxf(m, __shfl_xor(m, off, 64));
    __shared__ float wm[4];
    if ((t & 63) == 0) wm[t >> 6] = m;
    __syncthreads();
    m = fmaxf(fmaxf(wm[0], wm[1]), fmaxf(wm[2], wm[3]));

    float e = __expf(pooled - m);   // underflows to 0 for the dead lanes
#pragma unroll
    for (int off = 32; off > 0; off >>= 1)
        e += __shfl_xor(e, off, 64);
    __shared__ float wl[4];
    if ((t & 63) == 0) wl[t >> 6] = e;
    __syncthreads();
    if (t == 0) out[n] = 10.0f * (m + logf((wl[0] + wl[1]) + (wl[2] + wl[3])));
}

// ---------------------------------------------------------------------------
// Fallback path (proven 78.9 µs two-kernel version) in case cooperative
// launch is refused at capture time.
// ---------------------------------------------------------------------------
__global__ __launch_bounds__(256) void stage1_kernel(
    const float* __restrict__ x,
    const float* __restrict__ w,
    float* __restrict__ Sx,
    float* __restrict__ Sw)
{
    const int b = blockIdx.x;
    const int t = threadIdx.x;

    if (b < PLANES) {
        const float4* xp = (const float4*)(x + (size_t)b * HWVOL);
        float acc = 0.0f;
#pragma unroll
        for (int j = 0; j < 4; ++j) {
            float4 v = xp[t + 256 * j];
            acc += (v.x + v.y) + (v.z + v.w);
        }
#pragma unroll
        for (int off = 32; off > 0; off >>= 1)
            acc += __shfl_down(acc, off, 64);
        __shared__ float part[4];
        if ((t & 63) == 0) part[t >> 6] = acc;
        __syncthreads();
        if (t == 0) Sx[b] = (part[0] + part[1]) + (part[2] + part[3]);
    } else {
        const int o = (b - PLANES) * 256 + t;
        const float4* wp = (const float4*)(w + (size_t)o * 16);
        float4 a = wp[0], c = wp[1], d = wp[2], e = wp[3];
        Sw[o] = (((a.x + a.y) + (a.z + a.w)) + ((c.x + c.y) + (c.z + c.w))) +
                (((d.x + d.y) + (d.z + d.w)) + ((e.x + e.y) + (e.z + e.w)));
    }
}

__global__ __launch_bounds__(128) void final_kernel(
    const float* __restrict__ Sx,
    const float* __restrict__ Sw,
    const float* __restrict__ conv_bias,
    const float* __restrict__ extra_bias,
    float* __restrict__ out)
{
    const int n  = blockIdx.x;
    const int co = threadIdx.x;
    __shared__ float sxs[CIN];
    if (co < CIN) sxs[co] = Sx[n * CIN + co];
    __syncthreads();

    float acc = 0.0f;
#pragma unroll
    for (int ci = 0; ci < CIN; ++ci)
        acc = fmaf(sxs[ci], Sw[ci * COUT + co], acc);

    const float pooled = acc * OHW_INV + conv_bias[co] + extra_bias[co];

    float m = pooled;
#pragma unroll
    for (int off = 32; off > 0; off >>= 1)
        m = fmaxf(m, __shfl_xor(m, off, 64));
    __shared__ float wm[2];
    if ((co & 63) == 0) wm[co >> 6] = m;
    __syncthreads();
    m = fmaxf(wm[0], wm[1]);

    float e = __expf(pooled - m);
#pragma unroll
    for (int off = 32; off > 0; off >>= 1)
        e += __shfl_xor(e, off, 64);
    __shared__ float wl[2];
    if ((co & 63) == 0) wl[co >> 6] = e;
    __syncthreads();
    if (co == 0) out[n] = 10.0f * (m + logf(wl[0] + wl[1]));
}

extern "C" void kernel_launch(void* const* d_in, const int* in_sizes, int n_in,
                              void* d_out, int out_size, void* d_ws, size_t ws_size,
                              hipStream_t stream) {
    const float* x          = (const float*)d_in[0];
    const float* weight     = (const float*)d_in[1];
    const float* conv_bias  = (const float*)d_in[2];
    const float* extra_bias = (const float*)d_in[3];
    float* out = (float*)d_out;

    float* Sx = (float*)d_ws;          // 2048 floats
    float* Sw = Sx + PLANES;           // 8192 floats

    void* args[] = {&x, &weight, &conv_bias, &extra_bias, &Sx, &Sw, &out};
    hipError_t err = hipLaunchCooperativeKernel(
        fused_kernel, dim3(GRID), dim3(256), args, 0u, stream);
    if (err != hipSuccess) {
        // fallback: known-good two-kernel path
        stage1_kernel<<<PLANES + WBLKS, 256, 0, stream>>>(x, weight, Sx, Sw);
        final_kernel<<<Nn, 128, 0, stream>>>(Sx, Sw, conv_bias, extra_bias, out);
    }
}

// Round 2
// 161.290 us; speedup vs baseline: 1.0571x; 1.0571x over previous
//
#include <hip/hip_runtime.h>

// N=32, CIN=64, COUT=128, K=4, H=W=64
#define Nn     32
#define CIN    64
#define COUT   128
#define HWVOL  4096                 // H*W
#define PLANES (Nn * CIN)           // 2048 blocks, one x-plane each
#define SWVALS (CIN * COUT)         // 8192
#define OHW_INV (1.0f / 4489.0f)    // 1/67^2
#define NEGBIG (-3.0e38f)
#define MAGIC  0x5EC7A5A1u          // non-uniform bytes: cannot match a byte-pattern poison

// ---------------------------------------------------------------------------
// Single-dispatch fused kernel with targeted producer->consumer flag waits
// (NOT a grid barrier -- cg::grid.sync() measured ~70us of s_sleep stall in R1).
//
// Block b (0..2047): sums x-plane b (16KB, coalesced float4) -> Sx[b].
// Blocks 0..31 additionally compute a 256-wide chunk of the weight-tap sums Sw.
// Each writer publishes: data stores -> __syncthreads -> __threadfence
// (agent-scope release, L2 writeback) -> flags[b] = MAGIC (agent atomic).
//
// Blocks 0..31 then act as consumers: block n needs ONLY
//   flags[n*64 .. n*64+63]  (its image's plane sums; plane p is block p)
//   flags[0 .. 31]          (all Sw chunks)
// -> 96 flags, resolved ~1us after the last relevant writer, no global
// rendezvous. Then __threadfence (acquire/invalidate) and the proven
// GEMV + logsumexp from the 79us two-kernel version.
//
// Safety: writers never wait (no deadlock regardless of scheduling);
// flags are in workspace, re-poisoned each iteration by the harness fill,
// so no stale-MAGIC; spin is iteration-capped so a pathological case fails
// loudly instead of hanging.
// ---------------------------------------------------------------------------
__global__ __launch_bounds__(256, 8) void fused_kernel(
    const float* __restrict__ x,
    const float* __restrict__ w,
    const float* __restrict__ conv_bias,
    const float* __restrict__ extra_bias,
    float* __restrict__ Sx,
    float* __restrict__ Sw,
    unsigned* __restrict__ flags,
    float* __restrict__ out)
{
    const int b = blockIdx.x;
    const int t = threadIdx.x;

    // ---------------- Phase A: one plane sum per block (+ Sw chunk on 0..31)
    {
        const float4* xp = (const float4*)(x + (size_t)b * HWVOL);
        float acc = 0.0f;
#pragma unroll
        for (int j = 0; j < 4; ++j) {
            float4 v = xp[t + 256 * j];
            acc += (v.x + v.y) + (v.z + v.w);
        }
#pragma unroll
        for (int off = 32; off > 0; off >>= 1)
            acc += __shfl_down(acc, off, 64);
        __shared__ float part[4];
        if ((t & 63) == 0) part[t >> 6] = acc;
        __syncthreads();
        if (t == 0) Sx[b] = (part[0] + part[1]) + (part[2] + part[3]);

        if (b < 32) {
            const int o = b * 256 + t;               // 0..8191
            const float4* wp = (const float4*)(w + (size_t)o * 16);
            float4 a = wp[0], c = wp[1], d = wp[2], e = wp[3];
            Sw[o] = (((a.x + a.y) + (a.z + a.w)) + ((c.x + c.y) + (c.z + c.w))) +
                    (((d.x + d.y) + (d.z + d.w)) + ((e.x + e.y) + (e.z + e.w)));
        }
    }

    // Publish: make this block's Sx (and Sw chunk) agent-visible, then raise flag.
    __syncthreads();                       // all stores issued & drained (vmcnt0 before barrier)
    if (t == 0) {
        __threadfence();                   // agent-scope release: L2 writeback
        __hip_atomic_store(&flags[b], MAGIC, __ATOMIC_RELEASE, __HIP_MEMORY_SCOPE_AGENT);
    }

    // ---------------- Phase B: blocks 0..31, block n -> out[n]
    if (b >= Nn) return;
    const int n = b;

    // Targeted wait: 64 plane flags for image n + 32 Sw flags.
    if (t < 96) {
        const int idx = (t < 64) ? (n * 64 + t) : (t - 64);
        unsigned spins = 0;
        while (__hip_atomic_load(&flags[idx], __ATOMIC_RELAXED, __HIP_MEMORY_SCOPE_AGENT) != MAGIC) {
            __builtin_amdgcn_s_sleep(2);
            if (++spins > (1u << 22)) break;   // ~bounded: fail loudly, never hang
        }
    }
    __syncthreads();
    __threadfence();                       // acquire: invalidate caches before data reads

    __shared__ float sxs[CIN];
    if (t < CIN) sxs[t] = ((volatile const float*)Sx)[n * CIN + t];
    __syncthreads();

    float pooled = NEGBIG;
    if (t < COUT) {
        const volatile float* swv = (const volatile float*)Sw;
        float acc = 0.0f;
#pragma unroll 8
        for (int ci = 0; ci < CIN; ++ci)
            acc = fmaf(sxs[ci], swv[ci * COUT + t], acc);
        pooled = acc * OHW_INV + conv_bias[t] + extra_bias[t];
    }

    // logsumexp across the 128 live lanes (4 waves; waves 2,3 hold NEGBIG -> exp->0)
    float m = pooled;
#pragma unroll
    for (int off = 32; off > 0; off >>= 1)
        m = fmaxf(m, __shfl_xor(m, off, 64));
    __shared__ float wm[4];
    if ((t & 63) == 0) wm[t >> 6] = m;
    __syncthreads();
    m = fmaxf(fmaxf(wm[0], wm[1]), fmaxf(wm[2], wm[3]));

    float e = __expf(pooled - m);
#pragma unroll
    for (int off = 32; off > 0; off >>= 1)
        e += __shfl_xor(e, off, 64);
    __shared__ float wl[4];
    if ((t & 63) == 0) wl[t >> 6] = e;
    __syncthreads();
    if (t == 0) out[n] = 10.0f * (m + logf((wl[0] + wl[1]) + (wl[2] + wl[3])));
}

extern "C" void kernel_launch(void* const* d_in, const int* in_sizes, int n_in,
                              void* d_out, int out_size, void* d_ws, size_t ws_size,
                              hipStream_t stream) {
    const float* x          = (const float*)d_in[0];
    const float* weight     = (const float*)d_in[1];
    const float* conv_bias  = (const float*)d_in[2];
    const float* extra_bias = (const float*)d_in[3];
    float* out = (float*)d_out;

    float*    Sx    = (float*)d_ws;            // 2048 floats
    float*    Sw    = Sx + PLANES;             // 8192 floats
    unsigned* flags = (unsigned*)(Sw + SWVALS);// 2048 u32 (re-poisoned every iter)

    fused_kernel<<<PLANES, 256, 0, stream>>>(x, weight, conv_bias, extra_bias,
                                             Sx, Sw, flags, out);
}

// Round 3
// 90.658 us; speedup vs baseline: 1.8807x; 1.7791x over previous
//
#include <hip/hip_runtime.h>

// N=32, CIN=64, COUT=128, K=4, H=W=64
#define Nn     32
#define CIN    64
#define COUT   128
#define HWVOL  4096                 // H*W
#define PLANES (Nn * CIN)           // 2048 blocks, one x-plane each
#define OHW_INV (1.0f / 4489.0f)    // 1/67^2
#define NEGBIG (-3.0e38f)
#define MAGIC  0x5EC7A5A1u          // distinct bytes: no byte-pattern poison can match

// ---------------------------------------------------------------------------
// Single-dispatch fused kernel, ZERO fences (R2 lesson: agent __threadfence on
// gfx950 = whole-L2 writeback; 2048 of them serialized ~100us).
//
// Producer (all 2048 blocks): sum x-plane b -> pack {MAGIC, bits(sum)} into ONE
// 64-bit word, published with an agent-scope atomic EXCHANGE (RMW => resolves
// at the coherence point; data+flag in one word => no ordering required).
//
// Consumer (blocks 0..31): block n polls the 64 words of image n with
// fetch_add(0) (RMW => always reads the coherence point, cannot spin on a
// stale L2 line). Sw is NOT communicated: each consumer recomputes the
// 16-tap weight sums straight from w (512 KB, L2/L3-hot after producers ran),
// using the exact summation tree + ci-order of the proven 79us kernel
// => bit-identical math. Then logsumexp -> out[n].
//
// Deadlock-free: producers never wait; only 32/2048 blocks wait.
// ---------------------------------------------------------------------------
__global__ __launch_bounds__(256, 8) void fused_kernel(
    const float* __restrict__ x,
    const float* __restrict__ w,
    const float* __restrict__ conv_bias,
    const float* __restrict__ extra_bias,
    unsigned long long* __restrict__ Sx64,
    float* __restrict__ out)
{
    const int b = blockIdx.x;
    const int t = threadIdx.x;

    // ---------------- Phase A: one plane sum per block, publish as one word
    {
        const float4* xp = (const float4*)(x + (size_t)b * HWVOL);
        float acc = 0.0f;
#pragma unroll
        for (int j = 0; j < 4; ++j) {
            float4 v = xp[t + 256 * j];
            acc += (v.x + v.y) + (v.z + v.w);
        }
#pragma unroll
        for (int off = 32; off > 0; off >>= 1)
            acc += __shfl_down(acc, off, 64);
        __shared__ float part[4];
        if ((t & 63) == 0) part[t >> 6] = acc;
        __syncthreads();
        if (t == 0) {
            const float s = (part[0] + part[1]) + (part[2] + part[3]);
            const unsigned long long word =
                ((unsigned long long)MAGIC << 32) | (unsigned long long)__float_as_uint(s);
            // RMW publish: coherence-point visible, no fence needed.
            __hip_atomic_exchange(&Sx64[b], word, __ATOMIC_RELAXED,
                                  __HIP_MEMORY_SCOPE_AGENT);
        }
    }

    // ---------------- Phase B: blocks 0..31, block n -> out[n]
    if (b >= Nn) return;
    const int n = b;

    __shared__ float sxs[CIN];
    if (t < CIN) {
        const int idx = n * CIN + t;
        unsigned long long word;
        int spins = 0;
        for (;;) {
            // RMW poll: always round-trips to the coherence point.
            word = __hip_atomic_fetch_add(&Sx64[idx], 0ull, __ATOMIC_RELAXED,
                                          __HIP_MEMORY_SCOPE_AGENT);
            if ((unsigned)(word >> 32) == MAGIC) break;
            __builtin_amdgcn_s_sleep(1);
            if (++spins > (1 << 18)) break;   // bounded: fail loudly, never hang
        }
        sxs[t] = __uint_as_float((unsigned)word);
    }
    __syncthreads();

    // GEMV with on-the-fly tap sums (same tree + same ci order as proven kernel)
    float pooled = NEGBIG;
    if (t < COUT) {
        float acc = 0.0f;
#pragma unroll 4
        for (int ci = 0; ci < CIN; ++ci) {
            const float4* wp = (const float4*)(w + (size_t)(ci * COUT + t) * 16);
            float4 a = wp[0], c = wp[1], d = wp[2], e = wp[3];
            const float sw =
                (((a.x + a.y) + (a.z + a.w)) + ((c.x + c.y) + (c.z + c.w))) +
                (((d.x + d.y) + (d.z + d.w)) + ((e.x + e.y) + (e.z + e.w)));
            acc = fmaf(sxs[ci], sw, acc);
        }
        pooled = acc * OHW_INV + conv_bias[t] + extra_bias[t];
    }

    // logsumexp across the 128 live lanes (4 waves; waves 2,3 hold NEGBIG -> exp->0)
    float m = pooled;
#pragma unroll
    for (int off = 32; off > 0; off >>= 1)
        m = fmaxf(m, __shfl_xor(m, off, 64));
    __shared__ float wm[4];
    if ((t & 63) == 0) wm[t >> 6] = m;
    __syncthreads();
    m = fmaxf(fmaxf(wm[0], wm[1]), fmaxf(wm[2], wm[3]));

    float e = __expf(pooled - m);
#pragma unroll
    for (int off = 32; off > 0; off >>= 1)
        e += __shfl_xor(e, off, 64);
    __shared__ float wl[4];
    if ((t & 63) == 0) wl[t >> 6] = e;
    __syncthreads();
    if (t == 0) out[n] = 10.0f * (m + logf((wl[0] + wl[1]) + (wl[2] + wl[3])));
}

extern "C" void kernel_launch(void* const* d_in, const int* in_sizes, int n_in,
                              void* d_out, int out_size, void* d_ws, size_t ws_size,
                              hipStream_t stream) {
    const float* x          = (const float*)d_in[0];
    const float* weight     = (const float*)d_in[1];
    const float* conv_bias  = (const float*)d_in[2];
    const float* extra_bias = (const float*)d_in[3];
    float* out = (float*)d_out;

    unsigned long long* Sx64 = (unsigned long long*)d_ws;  // 2048 x u64 = 16 KB

    fused_kernel<<<PLANES, 256, 0, stream>>>(x, weight, conv_bias, extra_bias,
                                             Sx64, out);
}

// Round 4
// 81.402 us; speedup vs baseline: 2.0945x; 1.1137x over previous
//
#include <hip/hip_runtime.h>

// N=32, CIN=64, COUT=128, K=4, H=W=64
#define Nn     32
#define CIN    64
#define COUT   128
#define HWVOL  4096                 // H*W
#define PLANES (Nn * CIN)           // 2048 blocks, one x-plane each
#define SWVALS (CIN * COUT)         // 8192
#define OHW_INV (1.0f / 4489.0f)    // 1/67^2
#define NEGBIG (-3.0e38f)
#define MAGIC  0x5EC7A5A1u          // distinct bytes: no byte-pattern poison can match

// ---------------------------------------------------------------------------
// Single-dispatch, zero-fence fused kernel (R2 lesson: agent __threadfence =
// whole-L2 writeback, ~100us for 2048 of them; R3 lesson: recomputing tap sums
// in the 32-block tail = 16MB cold read by thin blocks, ~20us tail).
//
// Every communicated value is ONE packed u64 {hi=MAGIC, lo=float bits}
// published with an agent-scope atomic exchange (RMW -> resolves at the
// coherence point; data+flag in one word -> no ordering, no fences).
// Consumers poll with fetch_add(0) (RMW -> always reads the coherence point).
//
// Block b (0..2047): sums x-plane b -> Sx64[b].
// Blocks 0..31 FIRST compute a 256-value Sw chunk (exact R0 tree) -> Sw64[o],
// then their x-plane, then consume: block n polls the 64 Sx words of image n,
// cooperatively fetches all 8192 Sw words (batched independent RMWs ->
// pipelined) into LDS, then the proven GEMV + logsumexp -> out[n].
//
// Deadlock-free: producers never wait; only 32/2048 blocks wait, and all
// spins are iteration-bounded (fail loudly, never hang).
// ---------------------------------------------------------------------------
__global__ __launch_bounds__(256, 4) void fused_kernel(
    const float* __restrict__ x,
    const float* __restrict__ w,
    const float* __restrict__ conv_bias,
    const float* __restrict__ extra_bias,
    unsigned long long* __restrict__ Sx64,
    unsigned long long* __restrict__ Sw64,
    float* __restrict__ out)
{
    const int b = blockIdx.x;
    const int t = threadIdx.x;

    // ---- Sw chunk (blocks 0..31, before their plane so it's published early)
    if (b < 32) {
        const int o = b * 256 + t;                   // 0..8191 = ci*128+co
        const float4* wp = (const float4*)(w + (size_t)o * 16);
        float4 a = wp[0], c = wp[1], d = wp[2], e = wp[3];
        const float sw =
            (((a.x + a.y) + (a.z + a.w)) + ((c.x + c.y) + (c.z + c.w))) +
            (((d.x + d.y) + (d.z + d.w)) + ((e.x + e.y) + (e.z + e.w)));
        const unsigned long long word =
            ((unsigned long long)MAGIC << 32) | (unsigned long long)__float_as_uint(sw);
        __hip_atomic_exchange(&Sw64[o], word, __ATOMIC_RELAXED,
                              __HIP_MEMORY_SCOPE_AGENT);
    }

    // ---- Phase A: one x-plane sum per block (exact R0 tree), publish 1 word
    {
        const float4* xp = (const float4*)(x + (size_t)b * HWVOL);
        float acc = 0.0f;
#pragma unroll
        for (int j = 0; j < 4; ++j) {
            float4 v = xp[t + 256 * j];
            acc += (v.x + v.y) + (v.z + v.w);
        }
#pragma unroll
        for (int off = 32; off > 0; off >>= 1)
            acc += __shfl_down(acc, off, 64);
        __shared__ float part[4];
        if ((t & 63) == 0) part[t >> 6] = acc;
        __syncthreads();
        if (t == 0) {
            const float s = (part[0] + part[1]) + (part[2] + part[3]);
            const unsigned long long word =
                ((unsigned long long)MAGIC << 32) | (unsigned long long)__float_as_uint(s);
            __hip_atomic_exchange(&Sx64[b], word, __ATOMIC_RELAXED,
                                  __HIP_MEMORY_SCOPE_AGENT);
        }
    }

    // ---- Phase B: blocks 0..31 consume; block n -> out[n]
    if (b >= Nn) return;
    const int n = b;

    __shared__ float sws[SWVALS];   // 32 KB
    __shared__ float sxs[CIN];

    // Poll the 64 plane words of image n (one lane each; producers publish
    // before they could ever consume, so no circular wait).
    if (t < CIN) {
        const int idx = n * CIN + t;
        unsigned long long word;
        int spins = 0;
        for (;;) {
            word = __hip_atomic_fetch_add(&Sx64[idx], 0ull, __ATOMIC_RELAXED,
                                          __HIP_MEMORY_SCOPE_AGENT);
            if ((unsigned)(word >> 32) == MAGIC) break;
            __builtin_amdgcn_s_sleep(1);
            if (++spins > (1 << 18)) break;   // bounded: fail loudly, never hang
        }
        sxs[t] = __uint_as_float((unsigned)word);
    }

    // Cooperative Sw fetch: 256 threads x 32 words, batches of 8 independent
    // RMWs so they pipeline (R3's serial per-ci poll was the tail cost).
#pragma unroll
    for (int g = 0; g < 4; ++g) {
        unsigned long long wb[8];
#pragma unroll
        for (int j = 0; j < 8; ++j)
            wb[j] = __hip_atomic_fetch_add(&Sw64[(g * 8 + j) * 256 + t], 0ull,
                                           __ATOMIC_RELAXED, __HIP_MEMORY_SCOPE_AGENT);
#pragma unroll
        for (int j = 0; j < 8; ++j) {
            int spins = 0;
            while ((unsigned)(wb[j] >> 32) != MAGIC) {   // almost never taken
                __builtin_amdgcn_s_sleep(1);
                wb[j] = __hip_atomic_fetch_add(&Sw64[(g * 8 + j) * 256 + t], 0ull,
                                               __ATOMIC_RELAXED, __HIP_MEMORY_SCOPE_AGENT);
                if (++spins > (1 << 18)) break;
            }
            sws[(g * 8 + j) * 256 + t] = __uint_as_float((unsigned)wb[j]);
        }
    }
    __syncthreads();

    // GEMV (identical order to the proven 79us kernel) + pooled
    float pooled = NEGBIG;
    if (t < COUT) {
        float acc = 0.0f;
#pragma unroll 8
        for (int ci = 0; ci < CIN; ++ci)
            acc = fmaf(sxs[ci], sws[ci * COUT + t], acc);
        pooled = acc * OHW_INV + conv_bias[t] + extra_bias[t];
    }

    // logsumexp across 128 live lanes (4 waves; waves 2,3 hold NEGBIG -> exp->0)
    float m = pooled;
#pragma unroll
    for (int off = 32; off > 0; off >>= 1)
        m = fmaxf(m, __shfl_xor(m, off, 64));
    __shared__ float wm[4];
    if ((t & 63) == 0) wm[t >> 6] = m;
    __syncthreads();
    m = fmaxf(fmaxf(wm[0], wm[1]), fmaxf(wm[2], wm[3]));

    float e = __expf(pooled - m);
#pragma unroll
    for (int off = 32; off > 0; off >>= 1)
        e += __shfl_xor(e, off, 64);
    __shared__ float wl[4];
    if ((t & 63) == 0) wl[t >> 6] = e;
    __syncthreads();
    if (t == 0) out[n] = 10.0f * (m + logf((wl[0] + wl[1]) + (wl[2] + wl[3])));
}

extern "C" void kernel_launch(void* const* d_in, const int* in_sizes, int n_in,
                              void* d_out, int out_size, void* d_ws, size_t ws_size,
                              hipStream_t stream) {
    const float* x          = (const float*)d_in[0];
    const float* weight     = (const float*)d_in[1];
    const float* conv_bias  = (const float*)d_in[2];
    const float* extra_bias = (const float*)d_in[3];
    float* out = (float*)d_out;

    unsigned long long* Sx64 = (unsigned long long*)d_ws;   // 2048 u64
    unsigned long long* Sw64 = Sx64 + PLANES;               // 8192 u64

    fused_kernel<<<PLANES, 256, 0, stream>>>(x, weight, conv_bias, extra_bias,
                                             Sx64, Sw64, out);
}